// Round 7
// baseline (282.555 us; speedup 1.0000x reference)
//
#include <hip/hip_runtime.h>

typedef unsigned short u16;
typedef unsigned int u32;
typedef unsigned long long u64;
typedef __bf16 bf16x8 __attribute__((ext_vector_type(8)));
typedef float f32x4 __attribute__((ext_vector_type(4)));

#define MFMA16(a, b, c) __builtin_amdgcn_mfma_f32_16x16x32_bf16(a, b, c, 0, 0, 0)

static __device__ __forceinline__ u16 f2bf(float f) {
  union { float f; u32 u; } v; v.f = f;
  u32 u = v.u;
  u32 r = (u + 0x7FFFu + ((u >> 16) & 1u)) >> 16;  // RNE
  return (u16)r;
}

static __device__ __forceinline__ bf16x8 ld16(const u16* p) {
  return __builtin_bit_cast(bf16x8, *(const uint4*)p);
}

static __device__ __forceinline__ u64 u64min(u64 a, u64 b) { return a < b ? a : b; }

// In-wave bitonic sort of 64 u64 keys, ascending by lane. 21 compare-exchange levels.
static __device__ __forceinline__ u64 bitonic64(u64 v, int lane) {
#pragma unroll
  for (int k = 2; k <= 64; k <<= 1) {
#pragma unroll
    for (int j = k >> 1; j > 0; j >>= 1) {
      u64 o = __shfl_xor(v, j, 64);
      bool up = ((lane & k) == 0);
      bool lower = ((lane & j) == 0);
      u64 mn = v < o ? v : o;
      u64 mx = v < o ? o : v;
      v = (lower == up) ? mn : mx;
    }
  }
  return v;
}

// ---------------------------------------------------------------------------
// K2a: transpose+cast  src [B][64][4096] f32  ->  dst [B][4096][64] bf16
// ---------------------------------------------------------------------------
__global__ __launch_bounds__(256) void transpose_cast(const float* __restrict__ src,
                                                      u16* __restrict__ dst) {
  __shared__ __align__(4) u16 tile[64 * 66];
  const int t = threadIdx.x;
  const int b = blockIdx.x >> 6;
  const int n0 = (blockIdx.x & 63) << 6;
  const float* sp = src + ((size_t)b << 18);
#pragma unroll
  for (int i = 0; i < 16; i++) {
    int d = (i << 2) + (t >> 6);
    int n = t & 63;
    tile[n * 66 + d] = f2bf(sp[((size_t)d << 12) + n0 + n]);
  }
  __syncthreads();
  u16* dp = dst + ((size_t)(b * 4096 + n0) << 6);
#pragma unroll
  for (int i = 0; i < 8; i++) {
    int n = (i << 3) + (t >> 5);
    int dp2 = t & 31;
    *(u32*)(dp + n * 64 + (dp2 << 1)) = *(const u32*)(tile + n * 66 + (dp2 << 1));
  }
}

// ---------------------------------------------------------------------------
// K2b: cast/pad weights.  W1 [128][131] -> W1b [128][160] bf16 (zero pad),
// W2 [128][128] -> W2b bf16.
// ---------------------------------------------------------------------------
__global__ __launch_bounds__(256) void prep_w(const float* __restrict__ W1,
                                              const float* __restrict__ W2,
                                              u16* __restrict__ W1b,
                                              u16* __restrict__ W2b) {
  int t = blockIdx.x * 256 + threadIdx.x;
  if (t < 128 * 160) {
    int r = t / 160, c = t - r * 160;
    W1b[t] = (c < 131) ? f2bf(W1[r * 131 + c]) : (u16)0;
  } else {
    int u = t - 128 * 160;
    W2b[u] = f2bf(W2[u]);
  }
}

// ---------------------------------------------------------------------------
// K1a: s2[b][m] = ((bx^2 + by^2) + bz^2) — computed ONCE per candidate with
// the exact reference ops; knn consumes these stored bits (values identical
// to inline computation, removes 5 of 11 VALU ops per candidate-eval).
// ---------------------------------------------------------------------------
__global__ __launch_bounds__(256) void s2_prep(const float* __restrict__ xyz2,
                                               float* __restrict__ s2) {
  int i = blockIdx.x * 256 + threadIdx.x;  // 0..16383
  int b = i >> 12, m = i & 4095;
  const float* X2 = xyz2 + b * 12288;
  float bx = X2[m], by = X2[4096 + m], bz = X2[8192 + m];
  s2[i] = __fadd_rn(__fadd_rn(__fmul_rn(bx, bx), __fmul_rn(by, by)),
                    __fmul_rn(bz, bz));
}

// ---------------------------------------------------------------------------
// K1: wave-per-row KNN-16, zero barriers, keys in REGISTERS.
// Keys computed exactly once (round-5 lesson) and kept in VGPRs (round-4
// structure, which was numerically correct); launch_bounds(256,1) lifts the
// VGPR cap to 512 so keys[64] does NOT spill (round-4's failure was the
// (256,4) 128-VGPR cap). LDS = 2 KB surv only -> occupancy VGPR-limited
// (~4 waves/SIMD), double round 6's 68KB-LDS limit.
// Distance arithmetic bit-exact to rounds 3/4/6:
//   dot = fma(z,bz,fma(y,by,mul(x,bx)));  d2 = fl(fl(s1+s2) - fl(2*dot)),
//   s2 from s2_prep (same bits as inline).  key = monotone_u32(d2),
//   k64 = key<<32|m, ascending = exact lowest-index tie-break.
// Selection: per-lane top-1 -> bitonic-64 heads -> tau = 16th head (upper
// bound on global 16th) -> compact k64 <= tau from regs -> bitonic-64 ->
// lanes 0..15 store.  Cold path (S>64, astronomically rare): exact
// increasing-order wave-min extraction from the register keys.
// ---------------------------------------------------------------------------
__global__ __launch_bounds__(256, 1) void knn_kernel(const float* __restrict__ xyz1,
                                                     const float* __restrict__ xyz2,
                                                     const float* __restrict__ s2p,
                                                     int* __restrict__ knn) {
  __shared__ u64 surv[4][64];
  __shared__ u32 cnt[4];
  const int t = threadIdx.x;
  const int lane = t & 63;
  const int w = t >> 6;
  const int row = blockIdx.x * 4 + w;  // 0..16383
  const int b = row >> 12;
  const int n = row & 4095;
  const float* X1 = xyz1 + b * 12288;
  const float* X2 = xyz2 + b * 12288;
  const float* S2 = s2p + b * 4096;
  const float x = X1[n];
  const float y = X1[4096 + n];
  const float z = X1[8192 + n];
  const float s1 = __fadd_rn(__fadd_rn(__fmul_rn(x, x), __fmul_rn(y, y)),
                             __fmul_rn(z, z));
  const int base = lane << 6;  // this lane's 64 contiguous candidates

  // ---- pass 1: compute keys ONCE into registers, fold per-lane top-1 -----
  u32 keys[64];
  u64 head = ~0ull;
#pragma unroll
  for (int j = 0; j < 16; j++) {
    f32x4 bx = *(const f32x4*)(X2 + base + j * 4);
    f32x4 by = *(const f32x4*)(X2 + 4096 + base + j * 4);
    f32x4 bz = *(const f32x4*)(X2 + 8192 + base + j * 4);
    f32x4 s2 = *(const f32x4*)(S2 + base + j * 4);
#pragma unroll
    for (int e = 0; e < 4; e++) {
      float dt = __builtin_fmaf(z, bz[e], __builtin_fmaf(y, by[e], __fmul_rn(x, bx[e])));
      float d2 = __fsub_rn(__fadd_rn(s1, s2[e]), __fmul_rn(2.0f, dt));
      u32 bb = __float_as_uint(d2);
      u32 sgn = (u32)((int)bb >> 31);
      u32 key = bb ^ (sgn | 0x80000000u);  // monotone total order for floats
      keys[j * 4 + e] = key;
      u64 k64 = ((u64)key << 32) | (u32)(base + j * 4 + e);
      head = head < k64 ? head : k64;
    }
  }

  // tau = 16th smallest lane-head (valid upper bound on global 16th)
  u64 hs = bitonic64(head, lane);
  u64 tau = __shfl(hs, 15, 64);

  // ---- pass 2: compact k64 <= tau straight from the register keys --------
  if (lane == 0) cnt[w] = 0;
#pragma unroll
  for (int j = 0; j < 64; j++) {
    u64 k64 = ((u64)keys[j] << 32) | (u32)(base + j);
    if (k64 <= tau) {
      u32 slot = atomicAdd(&cnt[w], 1u);
      if (slot < 64) surv[w][slot] = k64;  // order irrelevant: fully sorted below
    }
  }
  u32 S = cnt[w];  // same-wave LDS ops are in program order: all adds visible

  if (S <= 64) {
    u64 v = (lane < (int)S) ? surv[w][lane] : ~0ull;
    v = bitonic64(v, lane);
    if (lane < 16) knn[row * 16 + lane] = (int)(v & 0xFFFFFFFFull);
  } else {
    // exact cold path: increasing-order extraction from the register keys
    u64 prev = 0;
    for (int r = 0; r < 16; r++) {
      u64 lm = ~0ull;
#pragma unroll
      for (int j = 0; j < 64; j++) {
        u64 k64 = ((u64)keys[j] << 32) | (u32)(base + j);
        if (k64 > prev && k64 < lm) lm = k64;
      }
      u64 gm = lm;
#pragma unroll
      for (int off = 32; off; off >>= 1) gm = u64min(gm, __shfl_xor(gm, off, 64));
      if (lane == 0) knn[row * 16 + r] = (int)(gm & 0xFFFFFFFFull);
      prev = gm;
    }
  }
}

// ---------------------------------------------------------------------------
// K3: fused gather + MLP (bf16 MFMA) + inverse-distance weighted reduce.
// 8 query rows per block -> M = 128 k-points.  F in LDS [128][168] bf16.
// H1 overwrites F cols 0..127 (each wave owns its 32 rows end-to-end).
// ---------------------------------------------------------------------------
__global__ __launch_bounds__(256) void mlp_kernel(
    const float* __restrict__ xyz1, const float* __restrict__ xyz2,
    const u16* __restrict__ p1t, const u16* __restrict__ p2t,
    const int* __restrict__ knn,
    const u16* __restrict__ W1b, const float* __restrict__ b1,
    const u16* __restrict__ W2b, const float* __restrict__ b2,
    float* __restrict__ out) {
  __shared__ __align__(16) u16 F[128 * 168];
  __shared__ __align__(16) float winv[128];
  __shared__ __align__(16) float wnorm[128];
  __shared__ __align__(16) float outbuf[128 * 12];
  const int t = threadIdx.x;
  const int g = blockIdx.x;
  const int b = g >> 9;
  const int rbase = (g & 511) << 3;

  // ---- Phase A: build F = [p1 | p2[idx] | dir | 0-pad] --------------------
  {
    const int m = t >> 1, half = t & 1;
    const int n1 = rbase + (m >> 4);
    const uint4* s1p = (const uint4*)(p1t + ((size_t)(b * 4096 + n1) << 6)) + half * 4;
    uint4* d1p = (uint4*)(F + m * 168) + half * 4;
    d1p[0] = s1p[0]; d1p[1] = s1p[1]; d1p[2] = s1p[2]; d1p[3] = s1p[3];
    const int idx = knn[(((size_t)(b * 4096 + n1)) << 4) + (m & 15)];
    const uint4* s2p = (const uint4*)(p2t + ((size_t)(b * 4096 + idx) << 6)) + half * 4;
    uint4* d2p = (uint4*)(F + m * 168 + 64) + half * 4;
    d2p[0] = s2p[0]; d2p[1] = s2p[1]; d2p[2] = s2p[2]; d2p[3] = s2p[3];
  }
  if (t < 128) {
    const int m = t;
    const int n1 = rbase + (m >> 4);
    const int idx = knn[(((size_t)(b * 4096 + n1)) << 4) + (m & 15)];
    const float* X1 = xyz1 + b * 12288;
    const float* X2 = xyz2 + b * 12288;
    float dx = X2[idx] - X1[n1];
    float dy = X2[4096 + idx] - X1[4096 + n1];
    float dz = X2[8192 + idx] - X1[8192 + n1];
    u32 u0 = (u32)f2bf(dx) | ((u32)f2bf(dy) << 16);
    u32 u1 = (u32)f2bf(dz);
    uint4 pk = make_uint4(u0, u1, 0u, 0u);
    *(uint4*)(F + m * 168 + 128) = pk;
    float d = sqrtf(dx * dx + dy * dy + dz * dz);
    winv[m] = 1.0f / fmaxf(d, 1e-10f);
  } else {
    const int m = t - 128;
    uint4 zz = make_uint4(0u, 0u, 0u, 0u);
    uint4* zp = (uint4*)(F + m * 168 + 136);
    zp[0] = zz; zp[1] = zz; zp[2] = zz; zp[3] = zz;
  }
  __syncthreads();
  if (t < 128) {
    const int r = t >> 4;
    float s = 0.f;
#pragma unroll
    for (int k = 0; k < 16; k++) s += winv[(r << 4) + k];
    wnorm[t] = winv[t] / s;
  }
  __syncthreads();

  const int lane = t & 63;
  const int wid = t >> 6;
  const int l15 = lane & 15;
  const int quad = lane >> 4;
  const int koff = quad << 3;

  const u16* Fr0 = F + (wid * 32 + l15) * 168 + koff;
  const u16* Fr1 = Fr0 + 16 * 168;

  // ---- GEMM1: [128x160] x W1b^T -> H1 [128x128] ---------------------------
  f32x4 acc[2][8];
  const f32x4 z4 = {0.f, 0.f, 0.f, 0.f};
#pragma unroll
  for (int i = 0; i < 2; i++)
#pragma unroll
    for (int j = 0; j < 8; j++) acc[i][j] = z4;

#pragma unroll
  for (int s = 0; s < 5; s++) {
    bf16x8 a0 = ld16(Fr0 + s * 32);
    bf16x8 a1 = ld16(Fr1 + s * 32);
#pragma unroll
    for (int nt = 0; nt < 8; nt++) {
      bf16x8 bf = ld16(W1b + (nt * 16 + l15) * 160 + s * 32 + koff);
      acc[0][nt] = MFMA16(a0, bf, acc[0][nt]);
      acc[1][nt] = MFMA16(a1, bf, acc[1][nt]);
    }
  }
#pragma unroll
  for (int nt = 0; nt < 8; nt++) {
    const float bv = b1[nt * 16 + l15];
#pragma unroll
    for (int mt = 0; mt < 2; mt++) {
      u16* hrow = F + (wid * 32 + mt * 16 + quad * 4) * 168 + nt * 16 + l15;
#pragma unroll
      for (int r = 0; r < 4; r++) {
        float zv = acc[mt][nt][r] + bv;
        zv = (zv >= 0.f) ? zv : 0.1f * zv;
        hrow[r * 168] = f2bf(zv);
      }
    }
  }
  __syncthreads();

  // ---- GEMM2: H1 [128x128] x W2b^T ---------------------------------------
  f32x4 acc2[2][8];
#pragma unroll
  for (int i = 0; i < 2; i++)
#pragma unroll
    for (int j = 0; j < 8; j++) acc2[i][j] = z4;

#pragma unroll
  for (int s = 0; s < 4; s++) {
    bf16x8 a0 = ld16(Fr0 + s * 32);
    bf16x8 a1 = ld16(Fr1 + s * 32);
#pragma unroll
    for (int nt = 0; nt < 8; nt++) {
      bf16x8 bf = ld16(W2b + (nt * 16 + l15) * 128 + s * 32 + koff);
      acc2[0][nt] = MFMA16(a0, bf, acc2[0][nt]);
      acc2[1][nt] = MFMA16(a1, bf, acc2[1][nt]);
    }
  }
  // ---- epilogue: leaky + bias, weighted sum over k, transpose via LDS -----
#pragma unroll
  for (int mt = 0; mt < 2; mt++) {
    const int mrow = wid * 2 + mt;
    const f32x4 w4 = *(const f32x4*)&wnorm[(mrow << 4) + (quad << 2)];
#pragma unroll
    for (int nt = 0; nt < 8; nt++) {
      const float bv = b2[nt * 16 + l15];
      float p = 0.f;
#pragma unroll
      for (int r = 0; r < 4; r++) {
        float zv = acc2[mt][nt][r] + bv;
        zv = (zv >= 0.f) ? zv : 0.1f * zv;
        p += zv * w4[r];
      }
      p += __shfl_xor(p, 16);
      p += __shfl_xor(p, 32);
      if (quad == 0) outbuf[(nt * 16 + l15) * 12 + mrow] = p;
    }
  }
  __syncthreads();
  {
    const int ch = t >> 1, half = t & 1;
    f32x4 v = *(const f32x4*)&outbuf[ch * 12 + (half << 2)];
    float* op = out + (((size_t)(b * 128 + ch)) << 12) + rbase + (half << 2);
    *(f32x4*)op = v;
  }
}

// ---------------------------------------------------------------------------
extern "C" void kernel_launch(void* const* d_in, const int* in_sizes, int n_in,
                              void* d_out, int out_size, void* d_ws, size_t ws_size,
                              hipStream_t stream) {
  const float* xyz1 = (const float*)d_in[0];
  const float* xyz2 = (const float*)d_in[1];
  const float* points1 = (const float*)d_in[2];
  const float* points2 = (const float*)d_in[3];
  const float* W1 = (const float*)d_in[4];
  const float* b1 = (const float*)d_in[5];
  const float* W2 = (const float*)d_in[6];
  const float* b2 = (const float*)d_in[7];
  float* out = (float*)d_out;

  char* ws = (char*)d_ws;
  int* knn = (int*)ws;                        // 16384*16*4      = 1,048,576 B
  u16* p1t = (u16*)(ws + 1048576);            // 2,097,152 B
  u16* p2t = (u16*)(ws + 3145728);            // 2,097,152 B
  u16* W1b = (u16*)(ws + 5242880);            // 40,960 B
  u16* W2b = (u16*)(ws + 5283840);            // 32,768 B
  float* s2 = (float*)(ws + 5316608);         // 16384*4 = 65,536 B

  hipLaunchKernelGGL(transpose_cast, dim3(256), dim3(256), 0, stream, points1, p1t);
  hipLaunchKernelGGL(transpose_cast, dim3(256), dim3(256), 0, stream, points2, p2t);
  hipLaunchKernelGGL(prep_w, dim3(144), dim3(256), 0, stream, W1, W2, W1b, W2b);
  hipLaunchKernelGGL(s2_prep, dim3(64), dim3(256), 0, stream, xyz2, s2);
  hipLaunchKernelGGL(knn_kernel, dim3(4096), dim3(256), 0, stream, xyz1, xyz2, s2, knn);
  hipLaunchKernelGGL(mlp_kernel, dim3(2048), dim3(256), 0, stream,
                     xyz1, xyz2, p1t, p2t, knn, W1b, b1, W2b, b2, out);
}

// Round 8
// 220.290 us; speedup vs baseline: 1.2826x; 1.2826x over previous
//
#include <hip/hip_runtime.h>

typedef unsigned short u16;
typedef unsigned int u32;
typedef unsigned long long u64;
typedef __bf16 bf16x8 __attribute__((ext_vector_type(8)));
typedef float f32x4 __attribute__((ext_vector_type(4)));

#define MFMA16(a, b, c) __builtin_amdgcn_mfma_f32_16x16x32_bf16(a, b, c, 0, 0, 0)

static __device__ __forceinline__ u16 f2bf(float f) {
  union { float f; u32 u; } v; v.f = f;
  u32 u = v.u;
  u32 r = (u + 0x7FFFu + ((u >> 16) & 1u)) >> 16;  // RNE
  return (u16)r;
}

static __device__ __forceinline__ bf16x8 ld16(const u16* p) {
  return __builtin_bit_cast(bf16x8, *(const uint4*)p);
}

static __device__ __forceinline__ u64 u64min(u64 a, u64 b) { return a < b ? a : b; }

// In-wave bitonic sort of 64 u64 keys, ascending by lane. 21 compare-exchange levels.
static __device__ __forceinline__ u64 bitonic64(u64 v, int lane) {
#pragma unroll
  for (int k = 2; k <= 64; k <<= 1) {
#pragma unroll
    for (int j = k >> 1; j > 0; j >>= 1) {
      u64 o = __shfl_xor(v, j, 64);
      bool up = ((lane & k) == 0);
      bool lower = ((lane & j) == 0);
      u64 mn = v < o ? v : o;
      u64 mx = v < o ? o : v;
      v = (lower == up) ? mn : mx;
    }
  }
  return v;
}

// ---------------------------------------------------------------------------
// K2a: transpose+cast  src [B][64][4096] f32  ->  dst [B][4096][64] bf16
// ---------------------------------------------------------------------------
__global__ __launch_bounds__(256) void transpose_cast(const float* __restrict__ src,
                                                      u16* __restrict__ dst) {
  __shared__ __align__(4) u16 tile[64 * 66];
  const int t = threadIdx.x;
  const int b = blockIdx.x >> 6;
  const int n0 = (blockIdx.x & 63) << 6;
  const float* sp = src + ((size_t)b << 18);
#pragma unroll
  for (int i = 0; i < 16; i++) {
    int d = (i << 2) + (t >> 6);
    int n = t & 63;
    tile[n * 66 + d] = f2bf(sp[((size_t)d << 12) + n0 + n]);
  }
  __syncthreads();
  u16* dp = dst + ((size_t)(b * 4096 + n0) << 6);
#pragma unroll
  for (int i = 0; i < 8; i++) {
    int n = (i << 3) + (t >> 5);
    int dp2 = t & 31;
    *(u32*)(dp + n * 64 + (dp2 << 1)) = *(const u32*)(tile + n * 66 + (dp2 << 1));
  }
}

// ---------------------------------------------------------------------------
// K2b: cast/pad weights.  W1 [128][131] -> W1b [128][160] bf16 (zero pad),
// W2 [128][128] -> W2b bf16.
// ---------------------------------------------------------------------------
__global__ __launch_bounds__(256) void prep_w(const float* __restrict__ W1,
                                              const float* __restrict__ W2,
                                              u16* __restrict__ W1b,
                                              u16* __restrict__ W2b) {
  int t = blockIdx.x * 256 + threadIdx.x;
  if (t < 128 * 160) {
    int r = t / 160, c = t - r * 160;
    W1b[t] = (c < 131) ? f2bf(W1[r * 131 + c]) : (u16)0;
  } else {
    int u = t - 128 * 160;
    W2b[u] = f2bf(W2[u]);
  }
}

// ---------------------------------------------------------------------------
// K1a: s2[b][m] = ((bx^2 + by^2) + bz^2) — computed ONCE with the exact
// reference ops; knn consumes these stored bits.
// ---------------------------------------------------------------------------
__global__ __launch_bounds__(256) void s2_prep(const float* __restrict__ xyz2,
                                               float* __restrict__ s2) {
  int i = blockIdx.x * 256 + threadIdx.x;  // 0..16383
  int b = i >> 12, m = i & 4095;
  const float* X2 = xyz2 + b * 12288;
  float bx = X2[m], by = X2[4096 + m], bz = X2[8192 + m];
  s2[i] = __fadd_rn(__fadd_rn(__fmul_rn(bx, bx), __fmul_rn(by, by)),
                    __fmul_rn(bz, bz));
}

// ---------------------------------------------------------------------------
// K1: KNN-16. LESSON (r7): lane->contiguous-chunk mapping (base=lane*64) is
// wave-uncoalesced (64 cache lines per load, TA-serialized). Now: candidate
// m = j*64 + lane (coalesced / LDS-conflict-free), X2 SoA staged in LDS once
// per block (48 KB), 32 rows per block (8 per wave), keys[64] in registers
// reused across rows (row loop NOT unrolled; launch_bounds(256,2) -> no
// spill). Keys computed exactly once per row (r5 lesson); selection order
// identical to rounds 3/4/6/7:
//   dot = fma(z,bz,fma(y,by,mul(x,bx)));  d2 = fl(fl(s1+s2) - fl(2*dot)),
//   s2 bits from s2_prep.  key = monotone_u32(d2); k64 = key<<32|m.
// Selection: per-lane top-1 -> bitonic-64 heads -> tau = 16th head (upper
// bound on global 16th) -> compact k64 <= tau -> bitonic-64 -> store.
// Cold path (S>64, astronomically rare): exact increasing-order extraction.
// ---------------------------------------------------------------------------
__global__ __launch_bounds__(256, 2) void knn_kernel(const float* __restrict__ xyz1,
                                                     const float* __restrict__ xyz2,
                                                     const float* __restrict__ s2p,
                                                     int* __restrict__ knn) {
  __shared__ float bxL[4096], byL[4096], bzL[4096];  // 48 KB
  __shared__ u64 surv[4][64];                        // 2 KB
  __shared__ u32 cnt[4];
  const int t = threadIdx.x;
  const int lane = t & 63;
  const int w = t >> 6;
  const int b = blockIdx.x >> 7;              // 512 blocks: 128 per batch
  const int rbase = (blockIdx.x & 127) << 5;  // 32 rows per block
  const float* X1 = xyz1 + b * 12288;
  const float* X2 = xyz2 + b * 12288;
  const float* S2 = s2p + b * 4096;

  // ---- stage X2 SoA into LDS (coalesced f32x4) ---------------------------
#pragma unroll
  for (int i = 0; i < 4; i++) {
    int e = (i * 256 + t) * 4;
    *(f32x4*)&bxL[e] = *(const f32x4*)&X2[e];
    *(f32x4*)&byL[e] = *(const f32x4*)&X2[4096 + e];
    *(f32x4*)&bzL[e] = *(const f32x4*)&X2[8192 + e];
  }
  __syncthreads();

#pragma unroll 1
  for (int r = 0; r < 8; r++) {
    const int n = rbase + (w << 3) + r;  // row within batch
    const int row = b * 4096 + n;
    const float x = X1[n];
    const float y = X1[4096 + n];
    const float z = X1[8192 + n];
    const float s1 = __fadd_rn(__fadd_rn(__fmul_rn(x, x), __fmul_rn(y, y)),
                               __fmul_rn(z, z));

    // ---- pass 1: keys ONCE into registers, fold per-lane top-1 -----------
    u32 keys[64];
    u64 head = ~0ull;
#pragma unroll
    for (int j = 0; j < 64; j++) {
      const int m = (j << 6) + lane;
      float bxv = bxL[m], byv = byL[m], bzv = bzL[m];
      float s2v = S2[m];  // coalesced, L1-resident
      float dt = __builtin_fmaf(z, bzv, __builtin_fmaf(y, byv, __fmul_rn(x, bxv)));
      float d2 = __fsub_rn(__fadd_rn(s1, s2v), __fmul_rn(2.0f, dt));
      u32 bb = __float_as_uint(d2);
      u32 sgn = (u32)((int)bb >> 31);
      u32 key = bb ^ (sgn | 0x80000000u);  // monotone total order for floats
      keys[j] = key;
      u64 k64 = ((u64)key << 32) | (u32)m;
      head = head < k64 ? head : k64;
    }

    // tau = 16th smallest lane-head (valid upper bound on global 16th)
    u64 hs = bitonic64(head, lane);
    u64 tau = __shfl(hs, 15, 64);

    // ---- pass 2: compact k64 <= tau from the register keys ---------------
    if (lane == 0) cnt[w] = 0;
#pragma unroll
    for (int j = 0; j < 64; j++) {
      u64 k64 = ((u64)keys[j] << 32) | (u32)((j << 6) + lane);
      if (k64 <= tau) {
        u32 slot = atomicAdd(&cnt[w], 1u);
        if (slot < 64) surv[w][slot] = k64;
      }
    }
    u32 S = cnt[w];  // same-wave LDS ops are in program order

    if (S <= 64) {
      u64 v = (lane < (int)S) ? surv[w][lane] : ~0ull;
      v = bitonic64(v, lane);
      if (lane < 16) knn[row * 16 + lane] = (int)(v & 0xFFFFFFFFull);
    } else {
      // exact cold path: increasing-order extraction from the register keys
      u64 prev = 0;
      for (int rr = 0; rr < 16; rr++) {
        u64 lm = ~0ull;
#pragma unroll
        for (int j = 0; j < 64; j++) {
          u64 k64 = ((u64)keys[j] << 32) | (u32)((j << 6) + lane);
          if (k64 > prev && k64 < lm) lm = k64;
        }
        u64 gm = lm;
#pragma unroll
        for (int off = 32; off; off >>= 1) gm = u64min(gm, __shfl_xor(gm, off, 64));
        if (lane == 0) knn[row * 16 + rr] = (int)(gm & 0xFFFFFFFFull);
        prev = gm;
      }
    }
  }
}

// ---------------------------------------------------------------------------
// K3: fused gather + MLP (bf16 MFMA) + inverse-distance weighted reduce.
// 8 query rows per block -> M = 128 k-points.  F in LDS [128][168] bf16.
// H1 overwrites F cols 0..127 (each wave owns its 32 rows end-to-end).
// ---------------------------------------------------------------------------
__global__ __launch_bounds__(256) void mlp_kernel(
    const float* __restrict__ xyz1, const float* __restrict__ xyz2,
    const u16* __restrict__ p1t, const u16* __restrict__ p2t,
    const int* __restrict__ knn,
    const u16* __restrict__ W1b, const float* __restrict__ b1,
    const u16* __restrict__ W2b, const float* __restrict__ b2,
    float* __restrict__ out) {
  __shared__ __align__(16) u16 F[128 * 168];
  __shared__ __align__(16) float winv[128];
  __shared__ __align__(16) float wnorm[128];
  __shared__ __align__(16) float outbuf[128 * 12];
  const int t = threadIdx.x;
  const int g = blockIdx.x;
  const int b = g >> 9;
  const int rbase = (g & 511) << 3;

  // ---- Phase A: build F = [p1 | p2[idx] | dir | 0-pad] --------------------
  {
    const int m = t >> 1, half = t & 1;
    const int n1 = rbase + (m >> 4);
    const uint4* s1p = (const uint4*)(p1t + ((size_t)(b * 4096 + n1) << 6)) + half * 4;
    uint4* d1p = (uint4*)(F + m * 168) + half * 4;
    d1p[0] = s1p[0]; d1p[1] = s1p[1]; d1p[2] = s1p[2]; d1p[3] = s1p[3];
    const int idx = knn[(((size_t)(b * 4096 + n1)) << 4) + (m & 15)];
    const uint4* s2p = (const uint4*)(p2t + ((size_t)(b * 4096 + idx) << 6)) + half * 4;
    uint4* d2p = (uint4*)(F + m * 168 + 64) + half * 4;
    d2p[0] = s2p[0]; d2p[1] = s2p[1]; d2p[2] = s2p[2]; d2p[3] = s2p[3];
  }
  if (t < 128) {
    const int m = t;
    const int n1 = rbase + (m >> 4);
    const int idx = knn[(((size_t)(b * 4096 + n1)) << 4) + (m & 15)];
    const float* X1 = xyz1 + b * 12288;
    const float* X2 = xyz2 + b * 12288;
    float dx = X2[idx] - X1[n1];
    float dy = X2[4096 + idx] - X1[4096 + n1];
    float dz = X2[8192 + idx] - X1[8192 + n1];
    u32 u0 = (u32)f2bf(dx) | ((u32)f2bf(dy) << 16);
    u32 u1 = (u32)f2bf(dz);
    uint4 pk = make_uint4(u0, u1, 0u, 0u);
    *(uint4*)(F + m * 168 + 128) = pk;
    float d = sqrtf(dx * dx + dy * dy + dz * dz);
    winv[m] = 1.0f / fmaxf(d, 1e-10f);
  } else {
    const int m = t - 128;
    uint4 zz = make_uint4(0u, 0u, 0u, 0u);
    uint4* zp = (uint4*)(F + m * 168 + 136);
    zp[0] = zz; zp[1] = zz; zp[2] = zz; zp[3] = zz;
  }
  __syncthreads();
  if (t < 128) {
    const int r = t >> 4;
    float s = 0.f;
#pragma unroll
    for (int k = 0; k < 16; k++) s += winv[(r << 4) + k];
    wnorm[t] = winv[t] / s;
  }
  __syncthreads();

  const int lane = t & 63;
  const int wid = t >> 6;
  const int l15 = lane & 15;
  const int quad = lane >> 4;
  const int koff = quad << 3;

  const u16* Fr0 = F + (wid * 32 + l15) * 168 + koff;
  const u16* Fr1 = Fr0 + 16 * 168;

  // ---- GEMM1: [128x160] x W1b^T -> H1 [128x128] ---------------------------
  f32x4 acc[2][8];
  const f32x4 z4 = {0.f, 0.f, 0.f, 0.f};
#pragma unroll
  for (int i = 0; i < 2; i++)
#pragma unroll
    for (int j = 0; j < 8; j++) acc[i][j] = z4;

#pragma unroll
  for (int s = 0; s < 5; s++) {
    bf16x8 a0 = ld16(Fr0 + s * 32);
    bf16x8 a1 = ld16(Fr1 + s * 32);
#pragma unroll
    for (int nt = 0; nt < 8; nt++) {
      bf16x8 bf = ld16(W1b + (nt * 16 + l15) * 160 + s * 32 + koff);
      acc[0][nt] = MFMA16(a0, bf, acc[0][nt]);
      acc[1][nt] = MFMA16(a1, bf, acc[1][nt]);
    }
  }
#pragma unroll
  for (int nt = 0; nt < 8; nt++) {
    const float bv = b1[nt * 16 + l15];
#pragma unroll
    for (int mt = 0; mt < 2; mt++) {
      u16* hrow = F + (wid * 32 + mt * 16 + quad * 4) * 168 + nt * 16 + l15;
#pragma unroll
      for (int r = 0; r < 4; r++) {
        float zv = acc[mt][nt][r] + bv;
        zv = (zv >= 0.f) ? zv : 0.1f * zv;
        hrow[r * 168] = f2bf(zv);
      }
    }
  }
  __syncthreads();

  // ---- GEMM2: H1 [128x128] x W2b^T ---------------------------------------
  f32x4 acc2[2][8];
#pragma unroll
  for (int i = 0; i < 2; i++)
#pragma unroll
    for (int j = 0; j < 8; j++) acc2[i][j] = z4;

#pragma unroll
  for (int s = 0; s < 4; s++) {
    bf16x8 a0 = ld16(Fr0 + s * 32);
    bf16x8 a1 = ld16(Fr1 + s * 32);
#pragma unroll
    for (int nt = 0; nt < 8; nt++) {
      bf16x8 bf = ld16(W2b + (nt * 16 + l15) * 128 + s * 32 + koff);
      acc2[0][nt] = MFMA16(a0, bf, acc2[0][nt]);
      acc2[1][nt] = MFMA16(a1, bf, acc2[1][nt]);
    }
  }
  // ---- epilogue: leaky + bias, weighted sum over k, transpose via LDS -----
#pragma unroll
  for (int mt = 0; mt < 2; mt++) {
    const int mrow = wid * 2 + mt;
    const f32x4 w4 = *(const f32x4*)&wnorm[(mrow << 4) + (quad << 2)];
#pragma unroll
    for (int nt = 0; nt < 8; nt++) {
      const float bv = b2[nt * 16 + l15];
      float p = 0.f;
#pragma unroll
      for (int r = 0; r < 4; r++) {
        float zv = acc2[mt][nt][r] + bv;
        zv = (zv >= 0.f) ? zv : 0.1f * zv;
        p += zv * w4[r];
      }
      p += __shfl_xor(p, 16);
      p += __shfl_xor(p, 32);
      if (quad == 0) outbuf[(nt * 16 + l15) * 12 + mrow] = p;
    }
  }
  __syncthreads();
  {
    const int ch = t >> 1, half = t & 1;
    f32x4 v = *(const f32x4*)&outbuf[ch * 12 + (half << 2)];
    float* op = out + (((size_t)(b * 128 + ch)) << 12) + rbase + (half << 2);
    *(f32x4*)op = v;
  }
}

// ---------------------------------------------------------------------------
extern "C" void kernel_launch(void* const* d_in, const int* in_sizes, int n_in,
                              void* d_out, int out_size, void* d_ws, size_t ws_size,
                              hipStream_t stream) {
  const float* xyz1 = (const float*)d_in[0];
  const float* xyz2 = (const float*)d_in[1];
  const float* points1 = (const float*)d_in[2];
  const float* points2 = (const float*)d_in[3];
  const float* W1 = (const float*)d_in[4];
  const float* b1 = (const float*)d_in[5];
  const float* W2 = (const float*)d_in[6];
  const float* b2 = (const float*)d_in[7];
  float* out = (float*)d_out;

  char* ws = (char*)d_ws;
  int* knn = (int*)ws;                        // 16384*16*4      = 1,048,576 B
  u16* p1t = (u16*)(ws + 1048576);            // 2,097,152 B
  u16* p2t = (u16*)(ws + 3145728);            // 2,097,152 B
  u16* W1b = (u16*)(ws + 5242880);            // 40,960 B
  u16* W2b = (u16*)(ws + 5283840);            // 32,768 B
  float* s2 = (float*)(ws + 5316608);         // 16384*4 = 65,536 B

  hipLaunchKernelGGL(transpose_cast, dim3(256), dim3(256), 0, stream, points1, p1t);
  hipLaunchKernelGGL(transpose_cast, dim3(256), dim3(256), 0, stream, points2, p2t);
  hipLaunchKernelGGL(prep_w, dim3(144), dim3(256), 0, stream, W1, W2, W1b, W2b);
  hipLaunchKernelGGL(s2_prep, dim3(64), dim3(256), 0, stream, xyz2, s2);
  hipLaunchKernelGGL(knn_kernel, dim3(512), dim3(256), 0, stream, xyz1, xyz2, s2, knn);
  hipLaunchKernelGGL(mlp_kernel, dim3(2048), dim3(256), 0, stream,
                     xyz1, xyz2, p1t, p2t, knn, W1b, b1, W2b, b2, out);
}

// Round 9
// 174.100 us; speedup vs baseline: 1.6229x; 1.2653x over previous
//
#include <hip/hip_runtime.h>

typedef unsigned short u16;
typedef unsigned int u32;
typedef unsigned long long u64;
typedef __bf16 bf16x8 __attribute__((ext_vector_type(8)));
typedef float f32x4 __attribute__((ext_vector_type(4)));

#define MFMA16(a, b, c) __builtin_amdgcn_mfma_f32_16x16x32_bf16(a, b, c, 0, 0, 0)

static __device__ __forceinline__ u16 f2bf(float f) {
  union { float f; u32 u; } v; v.f = f;
  u32 u = v.u;
  u32 r = (u + 0x7FFFu + ((u >> 16) & 1u)) >> 16;  // RNE
  return (u16)r;
}

static __device__ __forceinline__ bf16x8 ld16(const u16* p) {
  return __builtin_bit_cast(bf16x8, *(const uint4*)p);
}

static __device__ __forceinline__ u64 u64min(u64 a, u64 b) { return a < b ? a : b; }

// In-wave bitonic sort of 64 u64 keys, ascending by lane. 21 compare-exchange levels.
static __device__ __forceinline__ u64 bitonic64(u64 v, int lane) {
#pragma unroll
  for (int k = 2; k <= 64; k <<= 1) {
#pragma unroll
    for (int j = k >> 1; j > 0; j >>= 1) {
      u64 o = __shfl_xor(v, j, 64);
      bool up = ((lane & k) == 0);
      bool lower = ((lane & j) == 0);
      u64 mn = v < o ? v : o;
      u64 mx = v < o ? o : v;
      v = (lower == up) ? mn : mx;
    }
  }
  return v;
}

// ---------------------------------------------------------------------------
// K2a: transpose+cast  src [B][64][4096] f32  ->  dst [B][4096][64] bf16
// ---------------------------------------------------------------------------
__global__ __launch_bounds__(256) void transpose_cast(const float* __restrict__ src,
                                                      u16* __restrict__ dst) {
  __shared__ __align__(4) u16 tile[64 * 66];
  const int t = threadIdx.x;
  const int b = blockIdx.x >> 6;
  const int n0 = (blockIdx.x & 63) << 6;
  const float* sp = src + ((size_t)b << 18);
#pragma unroll
  for (int i = 0; i < 16; i++) {
    int d = (i << 2) + (t >> 6);
    int n = t & 63;
    tile[n * 66 + d] = f2bf(sp[((size_t)d << 12) + n0 + n]);
  }
  __syncthreads();
  u16* dp = dst + ((size_t)(b * 4096 + n0) << 6);
#pragma unroll
  for (int i = 0; i < 8; i++) {
    int n = (i << 3) + (t >> 5);
    int dp2 = t & 31;
    *(u32*)(dp + n * 64 + (dp2 << 1)) = *(const u32*)(tile + n * 66 + (dp2 << 1));
  }
}

// ---------------------------------------------------------------------------
// K2b: cast/pad weights.  W1 [128][131] -> W1b [128][160] bf16 (zero pad),
// W2 [128][128] -> W2b bf16.
// ---------------------------------------------------------------------------
__global__ __launch_bounds__(256) void prep_w(const float* __restrict__ W1,
                                              const float* __restrict__ W2,
                                              u16* __restrict__ W1b,
                                              u16* __restrict__ W2b) {
  int t = blockIdx.x * 256 + threadIdx.x;
  if (t < 128 * 160) {
    int r = t / 160, c = t - r * 160;
    W1b[t] = (c < 131) ? f2bf(W1[r * 131 + c]) : (u16)0;
  } else {
    int u = t - 128 * 160;
    W2b[u] = f2bf(W2[u]);
  }
}

// ---------------------------------------------------------------------------
// K1a: s2[b][m] = ((bx^2 + by^2) + bz^2) — computed ONCE with the exact
// reference ops; knn consumes these stored bits.
// ---------------------------------------------------------------------------
__global__ __launch_bounds__(256) void s2_prep(const float* __restrict__ xyz2,
                                               float* __restrict__ s2) {
  int i = blockIdx.x * 256 + threadIdx.x;  // 0..16383
  int b = i >> 12, m = i & 4095;
  const float* X2 = xyz2 + b * 12288;
  float bx = X2[m], by = X2[4096 + m], bz = X2[8192 + m];
  s2[i] = __fadd_rn(__fadd_rn(__fmul_rn(bx, bx), __fmul_rn(by, by)),
                    __fmul_rn(bz, bz));
}

// ---------------------------------------------------------------------------
// K1: KNN-16 (unchanged from round 8 — dropped below mlp in the profile).
// Candidate m = j*64 + lane (coalesced), X2 SoA staged in LDS, keys once in
// registers, tau-prefilter + bitonic sorts, exact lowest-index tie-break.
// ---------------------------------------------------------------------------
__global__ __launch_bounds__(256, 2) void knn_kernel(const float* __restrict__ xyz1,
                                                     const float* __restrict__ xyz2,
                                                     const float* __restrict__ s2p,
                                                     int* __restrict__ knn) {
  __shared__ float bxL[4096], byL[4096], bzL[4096];  // 48 KB
  __shared__ u64 surv[4][64];                        // 2 KB
  __shared__ u32 cnt[4];
  const int t = threadIdx.x;
  const int lane = t & 63;
  const int w = t >> 6;
  const int b = blockIdx.x >> 7;              // 512 blocks: 128 per batch
  const int rbase = (blockIdx.x & 127) << 5;  // 32 rows per block
  const float* X1 = xyz1 + b * 12288;
  const float* X2 = xyz2 + b * 12288;
  const float* S2 = s2p + b * 4096;

#pragma unroll
  for (int i = 0; i < 4; i++) {
    int e = (i * 256 + t) * 4;
    *(f32x4*)&bxL[e] = *(const f32x4*)&X2[e];
    *(f32x4*)&byL[e] = *(const f32x4*)&X2[4096 + e];
    *(f32x4*)&bzL[e] = *(const f32x4*)&X2[8192 + e];
  }
  __syncthreads();

#pragma unroll 1
  for (int r = 0; r < 8; r++) {
    const int n = rbase + (w << 3) + r;
    const int row = b * 4096 + n;
    const float x = X1[n];
    const float y = X1[4096 + n];
    const float z = X1[8192 + n];
    const float s1 = __fadd_rn(__fadd_rn(__fmul_rn(x, x), __fmul_rn(y, y)),
                               __fmul_rn(z, z));

    u32 keys[64];
    u64 head = ~0ull;
#pragma unroll
    for (int j = 0; j < 64; j++) {
      const int m = (j << 6) + lane;
      float bxv = bxL[m], byv = byL[m], bzv = bzL[m];
      float s2v = S2[m];
      float dt = __builtin_fmaf(z, bzv, __builtin_fmaf(y, byv, __fmul_rn(x, bxv)));
      float d2 = __fsub_rn(__fadd_rn(s1, s2v), __fmul_rn(2.0f, dt));
      u32 bb = __float_as_uint(d2);
      u32 sgn = (u32)((int)bb >> 31);
      u32 key = bb ^ (sgn | 0x80000000u);
      keys[j] = key;
      u64 k64 = ((u64)key << 32) | (u32)m;
      head = head < k64 ? head : k64;
    }

    u64 hs = bitonic64(head, lane);
    u64 tau = __shfl(hs, 15, 64);

    if (lane == 0) cnt[w] = 0;
#pragma unroll
    for (int j = 0; j < 64; j++) {
      u64 k64 = ((u64)keys[j] << 32) | (u32)((j << 6) + lane);
      if (k64 <= tau) {
        u32 slot = atomicAdd(&cnt[w], 1u);
        if (slot < 64) surv[w][slot] = k64;
      }
    }
    u32 S = cnt[w];

    if (S <= 64) {
      u64 v = (lane < (int)S) ? surv[w][lane] : ~0ull;
      v = bitonic64(v, lane);
      if (lane < 16) knn[row * 16 + lane] = (int)(v & 0xFFFFFFFFull);
    } else {
      u64 prev = 0;
      for (int rr = 0; rr < 16; rr++) {
        u64 lm = ~0ull;
#pragma unroll
        for (int j = 0; j < 64; j++) {
          u64 k64 = ((u64)keys[j] << 32) | (u32)((j << 6) + lane);
          if (k64 > prev && k64 < lm) lm = k64;
        }
        u64 gm = lm;
#pragma unroll
        for (int off = 32; off; off >>= 1) gm = u64min(gm, __shfl_xor(gm, off, 64));
        if (lane == 0) knn[row * 16 + rr] = (int)(gm & 0xFFFFFFFFull);
        prev = gm;
      }
    }
  }
}

// ---------------------------------------------------------------------------
// K3: fused gather + MLP + weighted reduce.  ROUND 9 RESTRUCTURE:
// waves split the N-dim (each wave owns 32 output channels = 2 nt tiles,
// covers ALL 128 M-rows) instead of splitting M.  W loads/lane drop 72->18
// (wave's W slice = 18 KB -> L1-resident across the CU's ~8 blocks; was
// 72 KB thrashing L1 = ~600 MB L2 streaming device-wide).  A-fragments now
// shared from LDS (what LDS is for).  MFMA order/fragments identical ->
// output bit-identical.  Extra hazard: all waves read all F rows in GEMM1
// while H1 overwrites F cols 0..127 -> barrier between GEMM1 reads and H1
// writes; wnorm folded after barrier 1 (4 barriers total, same as before).
// ---------------------------------------------------------------------------
__global__ __launch_bounds__(256, 3) void mlp_kernel(
    const float* __restrict__ xyz1, const float* __restrict__ xyz2,
    const u16* __restrict__ p1t, const u16* __restrict__ p2t,
    const int* __restrict__ knn,
    const u16* __restrict__ W1b, const float* __restrict__ b1,
    const u16* __restrict__ W2b, const float* __restrict__ b2,
    float* __restrict__ out) {
  __shared__ __align__(16) u16 F[128 * 168];
  __shared__ __align__(16) float winv[128];
  __shared__ __align__(16) float wnorm[128];
  __shared__ __align__(16) float outbuf[128 * 12];
  const int t = threadIdx.x;
  const int g = blockIdx.x;
  const int b = g >> 9;
  const int rbase = (g & 511) << 3;

  // ---- Phase A: build F = [p1 | p2[idx] | dir | 0-pad] --------------------
  {
    const int m = t >> 1, half = t & 1;
    const int n1 = rbase + (m >> 4);
    const uint4* s1p = (const uint4*)(p1t + ((size_t)(b * 4096 + n1) << 6)) + half * 4;
    uint4* d1p = (uint4*)(F + m * 168) + half * 4;
    d1p[0] = s1p[0]; d1p[1] = s1p[1]; d1p[2] = s1p[2]; d1p[3] = s1p[3];
    const int idx = knn[(((size_t)(b * 4096 + n1)) << 4) + (m & 15)];
    const uint4* s2p = (const uint4*)(p2t + ((size_t)(b * 4096 + idx) << 6)) + half * 4;
    uint4* d2p = (uint4*)(F + m * 168 + 64) + half * 4;
    d2p[0] = s2p[0]; d2p[1] = s2p[1]; d2p[2] = s2p[2]; d2p[3] = s2p[3];
  }
  if (t < 128) {
    const int m = t;
    const int n1 = rbase + (m >> 4);
    const int idx = knn[(((size_t)(b * 4096 + n1)) << 4) + (m & 15)];
    const float* X1 = xyz1 + b * 12288;
    const float* X2 = xyz2 + b * 12288;
    float dx = X2[idx] - X1[n1];
    float dy = X2[4096 + idx] - X1[4096 + n1];
    float dz = X2[8192 + idx] - X1[8192 + n1];
    u32 u0 = (u32)f2bf(dx) | ((u32)f2bf(dy) << 16);
    u32 u1 = (u32)f2bf(dz);
    uint4 pk = make_uint4(u0, u1, 0u, 0u);
    *(uint4*)(F + m * 168 + 128) = pk;
    float d = sqrtf(dx * dx + dy * dy + dz * dz);
    winv[m] = 1.0f / fmaxf(d, 1e-10f);
  } else {
    const int m = t - 128;
    uint4 zz = make_uint4(0u, 0u, 0u, 0u);
    uint4* zp = (uint4*)(F + m * 168 + 136);
    zp[0] = zz; zp[1] = zz; zp[2] = zz; zp[3] = zz;
  }
  __syncthreads();  // barrier 1: F + winv visible

  // wnorm in the GEMM1 shadow (reads winv, writes wnorm; no F hazard)
  if (t < 128) {
    const int r = t >> 4;
    float s = 0.f;
#pragma unroll
    for (int k = 0; k < 16; k++) s += winv[(r << 4) + k];
    wnorm[t] = winv[t] / s;
  }

  const int lane = t & 63;
  const int wid = t >> 6;
  const int l15 = lane & 15;
  const int quad = lane >> 4;
  const int koff = quad << 3;
  const int nbase = wid << 5;  // this wave's 32 output channels

  // ---- GEMM1: all 8 m-tiles x this wave's 2 n-tiles, K=160 ---------------
  f32x4 acc[8][2];
  const f32x4 z4 = {0.f, 0.f, 0.f, 0.f};
#pragma unroll
  for (int i = 0; i < 8; i++)
#pragma unroll
    for (int j = 0; j < 2; j++) acc[i][j] = z4;

#pragma unroll
  for (int s = 0; s < 5; s++) {
    bf16x8 bf0 = ld16(W1b + (nbase + l15) * 160 + s * 32 + koff);
    bf16x8 bf1 = ld16(W1b + (nbase + 16 + l15) * 160 + s * 32 + koff);
#pragma unroll
    for (int mt = 0; mt < 8; mt++) {
      bf16x8 a = ld16(F + (mt * 16 + l15) * 168 + s * 32 + koff);
      acc[mt][0] = MFMA16(a, bf0, acc[mt][0]);
      acc[mt][1] = MFMA16(a, bf1, acc[mt][1]);
    }
  }
  __syncthreads();  // barrier 2: all GEMM1 F-reads complete before H1 overwrite

  // H1 = leaky(acc + b1) -> F cols 0..127
  {
    const float bv0 = b1[nbase + l15];
    const float bv1 = b1[nbase + 16 + l15];
#pragma unroll
    for (int mt = 0; mt < 8; mt++) {
      u16* hrow = F + (mt * 16 + quad * 4) * 168;
#pragma unroll
      for (int r = 0; r < 4; r++) {
        float zv0 = acc[mt][0][r] + bv0;
        zv0 = (zv0 >= 0.f) ? zv0 : 0.1f * zv0;
        hrow[r * 168 + nbase + l15] = f2bf(zv0);
        float zv1 = acc[mt][1][r] + bv1;
        zv1 = (zv1 >= 0.f) ? zv1 : 0.1f * zv1;
        hrow[r * 168 + nbase + 16 + l15] = f2bf(zv1);
      }
    }
  }
  __syncthreads();  // barrier 3: H1 visible

  // ---- GEMM2: H1 [128x128] x W2b^T (this wave's 2 n-tiles) ---------------
  f32x4 acc2[8][2];
#pragma unroll
  for (int i = 0; i < 8; i++)
#pragma unroll
    for (int j = 0; j < 2; j++) acc2[i][j] = z4;

#pragma unroll
  for (int s = 0; s < 4; s++) {
    bf16x8 bf0 = ld16(W2b + (nbase + l15) * 128 + s * 32 + koff);
    bf16x8 bf1 = ld16(W2b + (nbase + 16 + l15) * 128 + s * 32 + koff);
#pragma unroll
    for (int mt = 0; mt < 8; mt++) {
      bf16x8 a = ld16(F + (mt * 16 + l15) * 168 + s * 32 + koff);
      acc2[mt][0] = MFMA16(a, bf0, acc2[mt][0]);
      acc2[mt][1] = MFMA16(a, bf1, acc2[mt][1]);
    }
  }

  // ---- epilogue: leaky + bias, weighted sum over k (16 rows = 1 mt tile) --
  {
    const float bv0 = b2[nbase + l15];
    const float bv1 = b2[nbase + 16 + l15];
#pragma unroll
    for (int mt = 0; mt < 8; mt++) {
      const f32x4 w4 = *(const f32x4*)&wnorm[(mt << 4) + (quad << 2)];
      float p0 = 0.f, p1 = 0.f;
#pragma unroll
      for (int r = 0; r < 4; r++) {
        float zv0 = acc2[mt][0][r] + bv0;
        zv0 = (zv0 >= 0.f) ? zv0 : 0.1f * zv0;
        p0 += zv0 * w4[r];
        float zv1 = acc2[mt][1][r] + bv1;
        zv1 = (zv1 >= 0.f) ? zv1 : 0.1f * zv1;
        p1 += zv1 * w4[r];
      }
      p0 += __shfl_xor(p0, 16); p0 += __shfl_xor(p0, 32);
      p1 += __shfl_xor(p1, 16); p1 += __shfl_xor(p1, 32);
      if (quad == 0) {
        outbuf[(nbase + l15) * 12 + mt] = p0;
        outbuf[(nbase + 16 + l15) * 12 + mt] = p1;
      }
    }
  }
  __syncthreads();  // barrier 4: outbuf visible
  {
    const int ch = t >> 1, half = t & 1;
    f32x4 v = *(const f32x4*)&outbuf[ch * 12 + (half << 2)];
    float* op = out + (((size_t)(b * 128 + ch)) << 12) + rbase + (half << 2);
    *(f32x4*)op = v;
  }
}

// ---------------------------------------------------------------------------
extern "C" void kernel_launch(void* const* d_in, const int* in_sizes, int n_in,
                              void* d_out, int out_size, void* d_ws, size_t ws_size,
                              hipStream_t stream) {
  const float* xyz1 = (const float*)d_in[0];
  const float* xyz2 = (const float*)d_in[1];
  const float* points1 = (const float*)d_in[2];
  const float* points2 = (const float*)d_in[3];
  const float* W1 = (const float*)d_in[4];
  const float* b1 = (const float*)d_in[5];
  const float* W2 = (const float*)d_in[6];
  const float* b2 = (const float*)d_in[7];
  float* out = (float*)d_out;

  char* ws = (char*)d_ws;
  int* knn = (int*)ws;                        // 16384*16*4      = 1,048,576 B
  u16* p1t = (u16*)(ws + 1048576);            // 2,097,152 B
  u16* p2t = (u16*)(ws + 3145728);            // 2,097,152 B
  u16* W1b = (u16*)(ws + 5242880);            // 40,960 B
  u16* W2b = (u16*)(ws + 5283840);            // 32,768 B
  float* s2 = (float*)(ws + 5316608);         // 16384*4 = 65,536 B

  hipLaunchKernelGGL(transpose_cast, dim3(256), dim3(256), 0, stream, points1, p1t);
  hipLaunchKernelGGL(transpose_cast, dim3(256), dim3(256), 0, stream, points2, p2t);
  hipLaunchKernelGGL(prep_w, dim3(144), dim3(256), 0, stream, W1, W2, W1b, W2b);
  hipLaunchKernelGGL(s2_prep, dim3(64), dim3(256), 0, stream, xyz2, s2);
  hipLaunchKernelGGL(knn_kernel, dim3(512), dim3(256), 0, stream, xyz1, xyz2, s2, knn);
  hipLaunchKernelGGL(mlp_kernel, dim3(2048), dim3(256), 0, stream,
                     xyz1, xyz2, p1t, p2t, knn, W1b, b1, W2b, b2, out);
}